// Round 12
// baseline (193.137 us; speedup 1.0000x reference)
//
#include <hip/hip_runtime.h>

#define NPTS 2048
#define TPB  384    // 6 waves/block; 4 cells/thread; capacity 1536
                    // own 1024 + 512 ghost wedge (>= 499 steps of cone)

typedef float v2f __attribute__((ext_vector_type(2)));
typedef float v4f __attribute__((ext_vector_type(4)));

// Barrier WITHOUT the vmcnt(0) drain __syncthreads() would emit:
// LDS writes must be visible (lgkmcnt), global stores may stay in flight.
#define EDGE_BARRIER() do {                                   \
    asm volatile("s_waitcnt lgkmcnt(0)" ::: "memory");        \
    __builtin_amdgcn_s_barrier();                             \
    asm volatile("" ::: "memory");                            \
} while (0)

__device__ __forceinline__ v2f s2(float x) { v2f v; v.x = x; v.y = x; return v; }

// packed fma: lowers to v_pk_fma_f32 (2 f32 FMA / lane / instr)
__device__ __forceinline__ v2f fma2(v2f a, v2f b, v2f c) {
#if __has_builtin(__builtin_elementwise_fma)
    return __builtin_elementwise_fma(a, b, c);
#else
    v2f r; r.x = fmaf(a.x, b.x, c.x); r.y = fmaf(a.y, b.y, c.y); return r;
#endif
}

// g = 0.5*f(u) = u*(0.75 + u*(9.375 + u*(-25.25 + u*(18.75 - 3.125 u^2))))
// p = f'(u)    = 1.5 + u*(37.5 + u*(-151.5 + u*(150 - 37.5 u^2)))
__device__ __forceinline__ void eval_gp2(v2f u, v2f& g, v2f& p) {
    const v2f uu = u * u;
    v2f gg = fma2(uu, s2(-3.125f), s2(18.75f));
    gg = fma2(u, gg, s2(-25.25f));
    gg = fma2(u, gg, s2(9.375f));
    gg = fma2(u, gg, s2(0.75f));
    g = u * gg;
    v2f pp = fma2(uu, s2(-37.5f), s2(150.0f));
    pp = fma2(u, pp, s2(-151.5f));
    pp = fma2(u, pp, s2(37.5f));
    p = fma2(u, pp, s2(1.5f));
}

#define FLUX(gl, gr, pl, pr, ul, ur) \
    fmaf(-0.5f * fmaxf(fabsf(pl), fabsf(pr)), (ur) - (ul), (gl) + (gr))

// Grid = 2 blocks per row (256 blocks -> all CUs). Block (r,h) evolves 1536
// cells autonomously (own 1024 + 512 ghost wedge; junk moves 1 cell/step ->
// own cells exact through t=499). Only EDGE cells (first/last of each
// thread's 4) cross threads: publish their (u,g,p); interior g,p are
// computed post-barrier in the shadow of the halo ds_read latency.
__global__ __launch_bounds__(TPB) void lxf_split(
    const float* __restrict__ init, float* __restrict__ out,
    int nbatch, int nsteps)
{
    __shared__ v2f EU[2][TPB];   // {u of cell c0, u of cell c0+3}
    __shared__ v2f EG[2][TPB];   // {g, g}
    __shared__ v2f EP[2][TPB];   // {p, p}

    const int blk = blockIdx.x;
    const int r   = blk >> 1;            // row
    const int h   = blk & 1;             // 0 -> global [0,1536), 1 -> [512,2048)
    const int tid = threadIdx.x;
    const int c0  = 4 * tid;             // local first cell
    const int gb  = h ? 512 : 0;
    const size_t rowoff = (size_t)r * NPTS;
    const float lam = 0.1024f;           // DT/DX (exact in f32)

    const bool st  = h ? (c0 >= 512) : (c0 < 1024);      // own-cell store mask
    const bool bcL = (h == 0) && (tid == 0);             // global cell 0
    const bool bcR = (h == 1) && (tid == TPB - 1);       // global cell 2047
    const int  tl  = (tid == 0)       ? 0   : tid - 1;
    const int  tr  = (tid == TPB - 1) ? tid : tid + 1;
    const int dist = h ? (507 - c0) : (c0 - 1025);       // wedge cone distance

    // ---- load init cells, eval EDGE g/p, write t=0, publish buf 0 ----
    v4f a = *reinterpret_cast<const v4f*>(init + rowoff + gb + c0);
    float s0 = a.x, s1 = a.y, s2v = a.z, s3 = a.w;

    v2f ue; ue.x = s0; ue.y = s3;
    v2f ge, pe;
    eval_gp2(ue, ge, pe);                // g,p of edge cells only

    if (st) *reinterpret_cast<v4f*>(out + rowoff + gb + c0) = a;

    EU[0][tid] = ue; EG[0][tid] = ge; EP[0][tid] = pe;
    EDGE_BARRIER();

    const size_t stride = (size_t)nbatch * NPTS;    // floats per step
    float* dstw = out + rowoff + gb + c0;

#define STEP(CUR, NXT) do {                                              \
    dstw += stride;                                                      \
    if (dist <= rem) {                                                   \
        /* halo reads issue first ... */                                 \
        float uL = EU[CUR][tl].y, gL = EG[CUR][tl].y, pL = EP[CUR][tl].y;\
        float uR = EU[CUR][tr].x, gR = EG[CUR][tr].x, pR = EP[CUR][tr].x;\
        /* ... interior g,p eval overlaps the read latency */            \
        v2f ui; ui.x = s1; ui.y = s2v;                                   \
        v2f gi, pi;                                                      \
        eval_gp2(ui, gi, pi);                                            \
        const float F1 = FLUX(ge.x, gi.x, pe.x, pi.x, s0, s1);           \
        const float F2 = FLUX(gi.x, gi.y, pi.x, pi.y, s1, s2v);          \
        const float F3 = FLUX(gi.y, ge.y, pi.y, pe.y, s2v, s3);          \
        if (tid == 0)       { uL = s0; gL = ge.x; pL = pe.x; }           \
        if (tid == TPB - 1) { uR = s3; gR = ge.y; pR = pe.y; }           \
        const float F0 = FLUX(gL, ge.x, pL, pe.x, uL, s0);               \
        const float F4 = FLUX(ge.y, gR, pe.y, pR, s3, uR);               \
        float n0 = fmaf(-lam, F1 - F0, s0);                              \
        float n1 = fmaf(-lam, F2 - F1, s1);                              \
        float n2 = fmaf(-lam, F3 - F2, s2v);                             \
        float n3 = fmaf(-lam, F4 - F3, s3);                              \
        if (bcL) n0 = n1;   /* u[0]   = u[1]   */                        \
        if (bcR) n3 = n2;   /* u[N-1] = u[N-2] */                        \
        s0 = n0; s1 = n1; s2v = n2; s3 = n3;                             \
        /* edge-pair eval + publish = the only pre-barrier chain */      \
        ue.x = n0; ue.y = n3;                                            \
        eval_gp2(ue, ge, pe);                                            \
        EU[NXT][tid] = ue; EG[NXT][tid] = ge; EP[NXT][tid] = pe;         \
        if (st) { v4f w; w.x = n0; w.y = n1; w.z = n2; w.w = n3;         \
                  *reinterpret_cast<v4f*>(dstw) = w; }                   \
    }                                                                    \
    --rem;                                                               \
    EDGE_BARRIER();                                                      \
} while (0)

    const int S  = nsteps - 1;   // 499 advance steps
    int rem = S - 1;             // steps remaining AFTER the current one
    const int P2 = S >> 1;       // 249
    for (int i = 0; i < P2; ++i) {
        STEP(0, 1);
        STEP(1, 0);
    }
    if (S & 1) STEP(0, 1);
#undef STEP
}

extern "C" void kernel_launch(void* const* d_in, const int* in_sizes, int n_in,
                              void* d_out, int out_size, void* d_ws, size_t ws_size,
                              hipStream_t stream) {
    const float* init = (const float*)d_in[0];
    float* out = (float*)d_out;

    const int nbatch = in_sizes[0] / NPTS;       // 128
    const int nsteps = out_size / in_sizes[0];   // 500

    hipLaunchKernelGGL(lxf_split, dim3(2 * nbatch), dim3(TPB), 0, stream,
                       init, out, nbatch, nsteps);
}